// Round 2
// baseline (2626.150 us; speedup 1.0000x reference)
//
#include <hip/hip_runtime.h>
#include <math.h>

#define BDIM 8
#define CDIM 64
#define HDIM 256
#define WDIM 256
#define H2D 128
#define W2D 128
#define HW  (HDIM*WDIM)   // 65536
#define HW2 (H2D*W2D)     // 16384
#define C4  256
#define C6  384

// ---------------- LN1 + DWT fused ----------------
// one thread per (b, h2, w2); two passes over C for LN stats then normalized DWT
__global__ __launch_bounds__(256) void k_ln_dwt(
    const float* __restrict__ X, const float* __restrict__ filt,
    const float* __restrict__ lw, const float* __restrict__ lb,
    float* __restrict__ S)
{
    const int b  = blockIdx.z;
    const int n  = blockIdx.x * 256 + threadIdx.x;   // over HW2
    const int h2 = n >> 7, w2 = n & 127;
    float f[16];
#pragma unroll
    for (int i = 0; i < 16; ++i) f[i] = filt[i];
    const float* xb = X + (size_t)b * CDIM * HW + (size_t)(2*h2) * WDIM + 2*w2;

    float s00=0.f,s01=0.f,s10=0.f,s11=0.f,q00=0.f,q01=0.f,q10=0.f,q11=0.f;
    for (int c = 0; c < CDIM; ++c) {
        const float* p = xb + (size_t)c * HW;
        float v00=p[0], v01=p[1], v10=p[WDIM], v11=p[WDIM+1];
        s00+=v00; q00+=v00*v00; s01+=v01; q01+=v01*v01;
        s10+=v10; q10+=v10*v10; s11+=v11; q11+=v11*v11;
    }
    const float inv = 1.0f/64.0f;
    float m00=s00*inv, m01=s01*inv, m10=s10*inv, m11=s11*inv;
    float r00=rsqrtf(fmaxf(q00*inv-m00*m00,0.f)+1e-6f);
    float r01=rsqrtf(fmaxf(q01*inv-m01*m01,0.f)+1e-6f);
    float r10=rsqrtf(fmaxf(q10*inv-m10*m10,0.f)+1e-6f);
    float r11=rsqrtf(fmaxf(q11*inv-m11*m11,0.f)+1e-6f);

    float* sp = S + ((size_t)b*C4)*HW2 + n;
    for (int c = 0; c < CDIM; ++c) {
        const float* p = xb + (size_t)c * HW;
        float wv = lw[c], bv = lb[c];
        float x00=(p[0]      -m00)*r00*wv+bv;
        float x01=(p[1]      -m01)*r01*wv+bv;
        float x10=(p[WDIM]   -m10)*r10*wv+bv;
        float x11=(p[WDIM+1] -m11)*r11*wv+bv;
#pragma unroll
        for (int k = 0; k < 4; ++k) {
            float acc = f[k*4+0]*x00 + f[k*4+1]*x01 + f[k*4+2]*x10 + f[k*4+3]*x11;
            sp[(size_t)(k*CDIM + c) * HW2] = acc;
        }
    }
}

// ---------------- pointwise conv as tiled SGEMM ----------------
// Y[b,m,n] = sum_k A[m,k] * X[b,k,n] + bias[m]
__global__ __launch_bounds__(256) void k_pw_gemm(
    const float* __restrict__ A, const float* __restrict__ bias,
    const float* __restrict__ X, float* __restrict__ Y,
    int M, int K, int N)
{
    const int b    = blockIdx.z;
    const int row0 = blockIdx.y * 64;
    const int n0   = blockIdx.x * 64;
    const float* Xb = X + (size_t)b * K * N;
    float* Yb = Y + (size_t)b * M * N;

    __shared__ __align__(16) float As[16][64];   // [k][m]
    __shared__ __align__(16) float Bs[16][64];   // [k][n]

    const int tid = threadIdx.x;
    const int tx  = tid & 15;      // n quadrant
    const int ty  = tid >> 4;      // m quadrant
    const int ar  = tid >> 2;          // 0..63 A row
    const int ak  = (tid & 3) * 4;     // A k offset
    const int bk  = tid >> 4;          // 0..15 B k row
    const int bc  = (tid & 15) * 4;    // B col

    float acc[4][4] = {};
    for (int k0 = 0; k0 < K; k0 += 16) {
        float4 a4 = *(const float4*)(A  + (size_t)(row0 + ar) * K + k0 + ak);
        float4 b4 = *(const float4*)(Xb + (size_t)(k0 + bk) * N + n0 + bc);
        __syncthreads();
        As[ak+0][ar] = a4.x; As[ak+1][ar] = a4.y;
        As[ak+2][ar] = a4.z; As[ak+3][ar] = a4.w;
        *(float4*)&Bs[bk][bc] = b4;
        __syncthreads();
#pragma unroll
        for (int kk = 0; kk < 16; ++kk) {
            float4 av = *(const float4*)&As[kk][ty*4];
            float4 bv = *(const float4*)&Bs[kk][tx*4];
            acc[0][0]+=av.x*bv.x; acc[0][1]+=av.x*bv.y; acc[0][2]+=av.x*bv.z; acc[0][3]+=av.x*bv.w;
            acc[1][0]+=av.y*bv.x; acc[1][1]+=av.y*bv.y; acc[1][2]+=av.y*bv.z; acc[1][3]+=av.y*bv.w;
            acc[2][0]+=av.z*bv.x; acc[2][1]+=av.z*bv.y; acc[2][2]+=av.z*bv.z; acc[2][3]+=av.z*bv.w;
            acc[3][0]+=av.w*bv.x; acc[3][1]+=av.w*bv.y; acc[3][2]+=av.w*bv.z; acc[3][3]+=av.w*bv.w;
        }
    }
#pragma unroll
    for (int i = 0; i < 4; ++i) {
        int row = row0 + ty*4 + i;
        float bi = bias[row];
        float4 o = make_float4(acc[i][0]+bi, acc[i][1]+bi, acc[i][2]+bi, acc[i][3]+bi);
        *(float4*)(Yb + (size_t)row * N + n0 + tx*4) = o;
    }
}

// ---------------- depthwise conv + exact GELU ----------------
template<int KS>
__global__ __launch_bounds__(256) void k_dw(
    const float* __restrict__ X, const float* __restrict__ Wd,
    const float* __restrict__ bd, float* __restrict__ Y, int Cn)
{
    const int b = blockIdx.z, ch = blockIdx.y;
    const int n = blockIdx.x * 256 + threadIdx.x;
    const int h = n >> 7, w = n & 127;
    const float* Xc = X + ((size_t)b * Cn + ch) * HW2;
    float wr[KS*KS];
#pragma unroll
    for (int i = 0; i < KS*KS; ++i) wr[i] = Wd[(size_t)ch * KS * KS + i];
    constexpr int P = KS / 2;
    float acc = bd[ch];
#pragma unroll
    for (int ky = 0; ky < KS; ++ky) {
        int yy = h + ky - P;
        if (yy < 0 || yy > 127) continue;
#pragma unroll
        for (int kx = 0; kx < KS; ++kx) {
            int xx = w + kx - P;
            if (xx < 0 || xx > 127) continue;
            acc += Xc[yy * 128 + xx] * wr[ky*KS + kx];
        }
    }
    float g = 0.5f * acc * (1.0f + erff(acc * 0.70710678118654752f));
    Y[((size_t)b * Cn + ch) * HW2 + n] = g;
}

// ---------------- IDWT + global-mean partial sums ----------------
__global__ __launch_bounds__(256) void k_idwt(
    const float* __restrict__ S, const float* __restrict__ filt,
    float* __restrict__ Xw, float* __restrict__ sumbuf)
{
    const int b = blockIdx.z, c = blockIdx.y;
    const int tid = threadIdx.x;
    const int n = blockIdx.x * 256 + tid;
    const int h2 = n >> 7, w2 = n & 127;
    float f[16];
#pragma unroll
    for (int i = 0; i < 16; ++i) f[i] = filt[i];
    float sv[4];
#pragma unroll
    for (int k = 0; k < 4; ++k)
        sv[k] = S[((size_t)b * C4 + k*CDIM + c) * HW2 + n];
    float* xp = Xw + ((size_t)b * CDIM + c) * HW + (size_t)(2*h2) * WDIM + 2*w2;
    float local = 0.f;
#pragma unroll
    for (int p = 0; p < 2; ++p)
#pragma unroll
        for (int q = 0; q < 2; ++q) {
            float v = sv[0]*f[0*4+p*2+q] + sv[1]*f[1*4+p*2+q]
                    + sv[2]*f[2*4+p*2+q] + sv[3]*f[3*4+p*2+q];
            xp[p*WDIM + q] = v;
            local += v;
        }
    __shared__ float red[256];
    red[tid] = local;
    __syncthreads();
    for (int off = 128; off > 0; off >>= 1) {
        if (tid < off) red[tid] += red[tid + off];
        __syncthreads();
    }
    if (tid == 0) atomicAdd(&sumbuf[b*CDIM + c], red[0]);
}

// ---------------- SCA attention vector (tiny) ----------------
__global__ void k_att(const float* __restrict__ sumbuf, const float* __restrict__ Wsca,
                      const float* __restrict__ bsca, float* __restrict__ att)
{
    int t = threadIdx.x;        // bc*64 threads
    int b = t >> 6, o = t & 63;
    float acc = bsca[o];
    const float s = 1.0f / (float)HW;
    for (int c = 0; c < 64; ++c)
        acc += Wsca[o*64 + c] * (sumbuf[b*64 + c] * s);
    att[t] = acc;
}

// ---------------- x*att -> pw3 -> y = x_in + x*beta ----------------
__global__ __launch_bounds__(256) void k_sca_pw3(
    const float* __restrict__ Xw, const float* __restrict__ Xin,
    const float* __restrict__ att, const float* __restrict__ W3,
    const float* __restrict__ b3, const float* __restrict__ beta,
    float* __restrict__ Yb)
{
    __shared__ __align__(16) float w3s[64*64];
    __shared__ float atts[64], b3s[64], bets[64];
    const int tid = threadIdx.x, b = blockIdx.z;
    for (int i = tid; i < 4096; i += 256) w3s[i] = W3[i];
    if (tid < 64) { atts[tid] = att[b*64 + tid]; b3s[tid] = b3[tid]; bets[tid] = beta[tid]; }
    __syncthreads();
    const size_t n = (size_t)blockIdx.x * 256 + tid;
    const size_t base = (size_t)b * 64 * HW + n;
    float v[64];
#pragma unroll
    for (int c = 0; c < 64; ++c) v[c] = Xw[base + (size_t)c * HW] * atts[c];
    for (int o = 0; o < 64; ++o) {
        float acc = b3s[o];
        const float4* wr = (const float4*)&w3s[o*64];
#pragma unroll
        for (int c4 = 0; c4 < 16; ++c4) {
            float4 wv = wr[c4]; int c = c4*4;
            acc += wv.x*v[c] + wv.y*v[c+1] + wv.z*v[c+2] + wv.w*v[c+3];
        }
        Yb[base + (size_t)o * HW] = Xin[base + (size_t)o * HW] + acc * bets[o];
    }
}

// ---------------- LN2 -> pw4 -> SimpleGate (h = a*g) ----------------
__global__ __launch_bounds__(256) void k_ln2_pw4(
    const float* __restrict__ Yb, const float* __restrict__ lw,
    const float* __restrict__ lb, const float* __restrict__ W4,
    const float* __restrict__ b4, float* __restrict__ Hb)
{
    __shared__ __align__(16) float w4s[128*64];
    __shared__ float b4s[128], lws[64], lbs[64];
    const int tid = threadIdx.x, b = blockIdx.z;
    for (int i = tid; i < 8192; i += 256) w4s[i] = W4[i];
    if (tid < 128) b4s[tid] = b4[tid];
    if (tid < 64) { lws[tid] = lw[tid]; lbs[tid] = lb[tid]; }
    __syncthreads();
    const size_t n = (size_t)blockIdx.x * 256 + tid;
    const size_t base = (size_t)b * 64 * HW + n;
    float t[64]; float sum = 0.f, sq = 0.f;
#pragma unroll
    for (int c = 0; c < 64; ++c) {
        float yv = Yb[base + (size_t)c * HW];
        t[c] = yv; sum += yv; sq += yv*yv;
    }
    float mu = sum * (1.0f/64.0f);
    float var = sq * (1.0f/64.0f) - mu*mu;
    float rs = rsqrtf(fmaxf(var, 0.f) + 1e-6f);
#pragma unroll
    for (int c = 0; c < 64; ++c) t[c] = (t[c] - mu) * rs * lws[c] + lbs[c];
    for (int j = 0; j < 64; ++j) {
        float aj = b4s[j], gj = b4s[j + 64];
        const float4* wa = (const float4*)&w4s[j*64];
        const float4* wg = (const float4*)&w4s[(j+64)*64];
#pragma unroll
        for (int c4 = 0; c4 < 16; ++c4) {
            float4 va = wa[c4], vg = wg[c4]; int c = c4*4;
            aj += va.x*t[c] + va.y*t[c+1] + va.z*t[c+2] + va.w*t[c+3];
            gj += vg.x*t[c] + vg.y*t[c+1] + vg.z*t[c+2] + vg.w*t[c+3];
        }
        Hb[((size_t)b * 64 + j) * HW + n] = aj * gj;
    }
}

// ---------------- pw5 + final residual ----------------
__global__ __launch_bounds__(256) void k_pw5_out(
    const float* __restrict__ Yb, const float* __restrict__ Hb,
    const float* __restrict__ W5, const float* __restrict__ b5,
    const float* __restrict__ gamma, float* __restrict__ Out)
{
    __shared__ __align__(16) float w5s[64*64];
    __shared__ float b5s[64], gs[64];
    const int tid = threadIdx.x, b = blockIdx.z;
    for (int i = tid; i < 4096; i += 256) w5s[i] = W5[i];
    if (tid < 64) { b5s[tid] = b5[tid]; gs[tid] = gamma[tid]; }
    __syncthreads();
    const size_t n = (size_t)blockIdx.x * 256 + tid;
    const size_t base = (size_t)b * 64 * HW + n;
    float hv[64];
#pragma unroll
    for (int j = 0; j < 64; ++j) hv[j] = Hb[base + (size_t)j * HW];
    for (int o = 0; o < 64; ++o) {
        float acc = b5s[o];
        const float4* wr = (const float4*)&w5s[o*64];
#pragma unroll
        for (int j4 = 0; j4 < 16; ++j4) {
            float4 wv = wr[j4]; int j = j4*4;
            acc += wv.x*hv[j] + wv.y*hv[j+1] + wv.z*hv[j+2] + wv.w*hv[j+3];
        }
        Out[base + (size_t)o * HW] = Yb[base + (size_t)o * HW] + acc * gs[o];
    }
}

extern "C" void kernel_launch(void* const* d_in, const int* in_sizes, int n_in,
                              void* d_out, int out_size, void* d_ws, size_t ws_size,
                              hipStream_t stream) {
    const float* x_in  = (const float*)d_in[0];
    const float* filt  = (const float*)d_in[1];
    const float* ln1_w = (const float*)d_in[2];
    const float* ln1_b = (const float*)d_in[3];
    const float* w1    = (const float*)d_in[4];
    const float* b1    = (const float*)d_in[5];
    const float* dw5   = (const float*)d_in[6];
    const float* bdw5  = (const float*)d_in[7];
    const float* dw3   = (const float*)d_in[8];
    const float* bdw3  = (const float*)d_in[9];
    const float* w2    = (const float*)d_in[10];
    const float* b2    = (const float*)d_in[11];
    const float* w_sca = (const float*)d_in[12];
    const float* b_sca = (const float*)d_in[13];
    const float* w3    = (const float*)d_in[14];
    const float* b3    = (const float*)d_in[15];
    const float* beta  = (const float*)d_in[16];
    const float* ln2_w = (const float*)d_in[17];
    const float* ln2_b = (const float*)d_in[18];
    const float* w4    = (const float*)d_in[19];
    const float* b4    = (const float*)d_in[20];
    const float* w5    = (const float*)d_in[21];
    const float* b5    = (const float*)d_in[22];
    const float* gamma = (const float*)d_in[23];
    float* out = (float*)d_out;

    // ---- workspace-adaptive batch chunking ----
    // per-batch arena: A (C6*HW2 floats) + B (C6*HW2 floats) = 50,331,648 B
    // all 64-ch/HW and 256-ch/HW2 tensors packed into dead sub-regions (see schedule)
    const size_t PB_A   = (size_t)C6 * HW2;                 // floats, per batch
    const size_t PB_ARE = 2 * PB_A;                          // floats, per batch
    int bc = 8;
    while (bc > 1 && (size_t)bc * PB_ARE * 4 + (size_t)bc * 512 > ws_size) bc >>= 1;
    const int nchunk = BDIM / bc;

    float* ws = (float*)d_ws;
    float* Abuf  = ws;                          // [bc * C6 * HW2]
    float* Bbuf  = ws + (size_t)bc * PB_A;      // [bc * C6 * HW2]
    float* stats = ws + (size_t)bc * PB_ARE;    // bc*64 sums + bc*64 att
    float* attv  = stats + (size_t)bc * 64;

    // packed views (all within A/B regions; lifetimes verified):
    float* dwt_s  = Bbuf;                       // [bc,256,HW2] live: ln_dwt -> pw1
    float* p1     = Abuf;                       // [bc,384,HW2] live: pw1 -> dw5
    float* d5     = Bbuf;                       // [bc,384,HW2] live: dw5 -> dw3
    float* d3     = Abuf;                       // [bc,384,HW2] live: dw3 -> pw2
    float* p2     = Bbuf;                       // [bc,256,HW2] live: pw2 -> idwt
    float* xw     = Abuf;                       // [bc,64,HW]   live: idwt -> sca_pw3
    float* ybuf   = Bbuf;                       // [bc,64,HW]   live: sca_pw3 -> pw5
    float* hbuf   = Abuf;                       // [bc,64,HW]   live: ln2_pw4 -> pw5

    for (int ck = 0; ck < nchunk; ++ck) {
        const float* xin_c = x_in + (size_t)ck * bc * CDIM * HW;
        float* out_c = out + (size_t)ck * bc * CDIM * HW;

        hipMemsetAsync(stats, 0, (size_t)bc * 64 * sizeof(float), stream);

        // 1) LN1 + DWT : x_in -> dwt_s [bc,256,HW2]
        k_ln_dwt<<<dim3(HW2/256, 1, bc), 256, 0, stream>>>(xin_c, filt, ln1_w, ln1_b, dwt_s);
        // 2) pw1 : dwt_s -> p1 [bc,384,HW2]
        k_pw_gemm<<<dim3(HW2/64, C6/64, bc), 256, 0, stream>>>(w1, b1, dwt_s, p1, C6, C4, HW2);
        // 3) dw5 + gelu : p1 -> d5
        k_dw<5><<<dim3(HW2/256, C6, bc), 256, 0, stream>>>(p1, dw5, bdw5, d5, C6);
        // 4) dw3 + gelu : d5 -> d3
        k_dw<3><<<dim3(HW2/256, C6, bc), 256, 0, stream>>>(d5, dw3, bdw3, d3, C6);
        // 5) pw2 : d3 -> p2 [bc,256,HW2]
        k_pw_gemm<<<dim3(HW2/64, C4/64, bc), 256, 0, stream>>>(w2, b2, d3, p2, C4, C6, HW2);
        // 6) IDWT + spatial-sum : p2 -> xw (as [bc,64,HW]), sums into stats
        k_idwt<<<dim3(HW2/256, CDIM, bc), 256, 0, stream>>>(p2, filt, xw, stats);
        // 7) attention vector
        k_att<<<1, bc*64, 0, stream>>>(stats, w_sca, b_sca, attv);
        // 8) x*att -> pw3 -> y = x_in + x*beta : -> ybuf
        k_sca_pw3<<<dim3(HW/256, 1, bc), 256, 0, stream>>>(xw, xin_c, attv, w3, b3, beta, ybuf);
        // 9) LN2 -> pw4 -> gate : ybuf -> hbuf
        k_ln2_pw4<<<dim3(HW/256, 1, bc), 256, 0, stream>>>(ybuf, ln2_w, ln2_b, w4, b4, hbuf);
        // 10) pw5 + residual : -> out
        k_pw5_out<<<dim3(HW/256, 1, bc), 256, 0, stream>>>(ybuf, hbuf, w5, b5, gamma, out_c);
    }
}

// Round 7
// 1315.603 us; speedup vs baseline: 1.9962x; 1.9962x over previous
//
#include <hip/hip_runtime.h>
#include <math.h>

#define BDIM 8
#define CDIM 64
#define HDIM 256
#define WDIM 256
#define HW  (HDIM*WDIM)   // 65536
#define HW2 (128*128)     // 16384
#define C4  256
#define C6  384

typedef __attribute__((ext_vector_type(8))) short short8;
typedef __attribute__((ext_vector_type(4))) float f32x4;

__device__ __forceinline__ ushort f2bf(float x) {
    unsigned u = __float_as_uint(x);
    unsigned r = (u + 0x7fffu + ((u >> 16) & 1u)) >> 16;
    return (ushort)r;
}
__device__ __forceinline__ float bf2f(ushort v) {
    return __uint_as_float(((unsigned)v) << 16);
}
__device__ __forceinline__ float gelu(float x) {
    return 0.5f * x * (1.0f + erff(x * 0.70710678118654752f));
}

// ---------------- weights f32 -> bf16 ----------------
__global__ void k_cvt_bf16(const float* __restrict__ src, ushort* __restrict__ dst, int n) {
    int i = blockIdx.x * 256 + threadIdx.x;
    if (i < n) dst[i] = f2bf(src[i]);
}

// ---------------- LN1 + DWT fused (shuffle-split channel loop) ----------------
// thread: (pair of w2, channel-quarter). 4 lanes (cg) share one pixel-pair.
__global__ __launch_bounds__(256) void k_ln_dwt(
    const float* __restrict__ X, const float* __restrict__ filt,
    const float* __restrict__ lw, const float* __restrict__ lb,
    ushort* __restrict__ S)
{
    const int b   = blockIdx.z;
    const int tid = threadIdx.x;
    const int pb  = tid >> 2;           // pair-in-block 0..63
    const int cg  = tid & 3;            // channel quarter
    const int p   = blockIdx.x * 64 + pb;   // 0..8191
    const int h2  = p >> 6;
    const int wp  = p & 63;             // w2 pair: w2 = 2wp, 2wp+1
    float f[16];
#pragma unroll
    for (int i = 0; i < 16; ++i) f[i] = filt[i];

    const float* xb = X + (size_t)b * CDIM * HW + (size_t)(2 * h2) * WDIM + 4 * wp;
    const int c0 = cg * 16;

    float s0 = 0.f, q0 = 0.f, s1 = 0.f, q1 = 0.f;
    for (int c = c0; c < c0 + 16; ++c) {
        const float* pr = xb + (size_t)c * HW;
        float4 r0 = *(const float4*)pr;
        float4 r1 = *(const float4*)(pr + WDIM);
        s0 += r0.x + r0.y + r1.x + r1.y;
        q0 += r0.x*r0.x + r0.y*r0.y + r1.x*r1.x + r1.y*r1.y;
        s1 += r0.z + r0.w + r1.z + r1.w;
        q1 += r0.z*r0.z + r0.w*r0.w + r1.z*r1.z + r1.w*r1.w;
    }
    s0 += __shfl_xor(s0, 1); q0 += __shfl_xor(q0, 1);
    s1 += __shfl_xor(s1, 1); q1 += __shfl_xor(q1, 1);
    s0 += __shfl_xor(s0, 2); q0 += __shfl_xor(q0, 2);
    s1 += __shfl_xor(s1, 2); q1 += __shfl_xor(q1, 2);
    const float inv = 1.0f / 64.0f;
    float m0 = s0 * inv, m1 = s1 * inv;
    float rs0 = rsqrtf(fmaxf(q0 * inv - m0 * m0, 0.f) + 1e-6f);
    float rs1 = rsqrtf(fmaxf(q1 * inv - m1 * m1, 0.f) + 1e-6f);

    const int n = h2 * 128 + 2 * wp;    // even
    ushort* Sp = S + (size_t)b * C4 * HW2;
    for (int c = c0; c < c0 + 16; ++c) {
        const float* pr = xb + (size_t)c * HW;
        float4 r0 = *(const float4*)pr;
        float4 r1 = *(const float4*)(pr + WDIM);
        float wv = lw[c], bv = lb[c];
        // pixel 0 (w2=2wp): cols 4wp,4wp+1 ; pixel 1: cols 4wp+2,4wp+3
        float a00 = (r0.x - m0) * rs0 * wv + bv;
        float a01 = (r0.y - m0) * rs0 * wv + bv;
        float a10 = (r1.x - m0) * rs0 * wv + bv;
        float a11 = (r1.y - m0) * rs0 * wv + bv;
        float b00 = (r0.z - m1) * rs1 * wv + bv;
        float b01 = (r0.w - m1) * rs1 * wv + bv;
        float b10 = (r1.z - m1) * rs1 * wv + bv;
        float b11 = (r1.w - m1) * rs1 * wv + bv;
#pragma unroll
        for (int k = 0; k < 4; ++k) {
            float va = f[k*4+0]*a00 + f[k*4+1]*a01 + f[k*4+2]*a10 + f[k*4+3]*a11;
            float vb = f[k*4+0]*b00 + f[k*4+1]*b01 + f[k*4+2]*b10 + f[k*4+3]*b11;
            unsigned pk = (unsigned)f2bf(va) | ((unsigned)f2bf(vb) << 16);
            *(unsigned*)&Sp[(size_t)(k * CDIM + c) * HW2 + n] = pk;
        }
    }
}

// ---------------- pointwise conv: bf16 MFMA GEMM ----------------
// Y[b,m,n] = sum_k A[m,k]*X[b,k,n] + bias[m].  A bf16 [M][K], X bf16 [K][N].
// BM=128, BN=128, BK=64. 256 threads = 4 waves (2x2 of 64x64).
template<bool BF16OUT>
__global__ __launch_bounds__(256) void k_pw_mfma(
    const ushort* __restrict__ A, const float* __restrict__ bias,
    const ushort* __restrict__ Xg, void* __restrict__ Yg,
    int M, int K, int N)
{
    const int b  = blockIdx.z;
    const int m0 = blockIdx.y * 128;
    const int n0 = blockIdx.x * 128;
    const ushort* X = Xg + (size_t)b * K * N;

    __shared__ ushort As[128][72];   // [m][k] k-minor, pad 8
    __shared__ ushort Bs[128][72];   // [n][k] k-minor, pad 8

    const int tid = threadIdx.x;
    const int l   = tid & 63, w = tid >> 6;
    const int wr  = w >> 1, wc = w & 1;
    const int lr  = l & 15, lg = l >> 4;

    // staging decomposition
    const int blr = tid & 15;          // B: k-chunk selector
    const int bng = tid >> 4;          // B: n-group 0..15
    const int k0c = blr * 4;
    const int n0t = bng * 8;

    f32x4 acc[4][4];
#pragma unroll
    for (int i = 0; i < 4; ++i)
#pragma unroll
        for (int j = 0; j < 4; ++j) acc[i][j] = (f32x4){0.f, 0.f, 0.f, 0.f};

    for (int k0 = 0; k0 < K; k0 += 64) {
        // global loads first (prefetch before barrier)
        uint4 av[4], bv[4];
#pragma unroll
        for (int i = 0; i < 4; ++i) {
            int c = tid + 256 * i;          // 0..1023
            int m = c & 127, kc = c >> 7;   // kc 0..7
            av[i] = *(const uint4*)(A + (size_t)(m0 + m) * K + k0 + kc * 8);
        }
#pragma unroll
        for (int dk = 0; dk < 4; ++dk)
            bv[dk] = *(const uint4*)(X + (size_t)(k0 + k0c + dk) * N + n0 + n0t);

        __syncthreads();
#pragma unroll
        for (int i = 0; i < 4; ++i) {
            int c = tid + 256 * i;
            int m = c & 127, kc = c >> 7;
            *(uint4*)&As[m][kc * 8] = av[i];
        }
#pragma unroll
        for (int j = 0; j < 8; ++j) {
            ushort4 wv;
            wv.x = ((const ushort*)&bv[0])[j];
            wv.y = ((const ushort*)&bv[1])[j];
            wv.z = ((const ushort*)&bv[2])[j];
            wv.w = ((const ushort*)&bv[3])[j];
            *(ushort4*)&Bs[n0t + j][k0c] = wv;
        }
        __syncthreads();

#pragma unroll
        for (int ks = 0; ks < 2; ++ks) {
            short8 af[4], bf[4];
#pragma unroll
            for (int mf = 0; mf < 4; ++mf)
                af[mf] = *(const short8*)&As[wr * 64 + mf * 16 + lr][ks * 32 + lg * 8];
#pragma unroll
            for (int nf = 0; nf < 4; ++nf)
                bf[nf] = *(const short8*)&Bs[wc * 64 + nf * 16 + lr][ks * 32 + lg * 8];
#pragma unroll
            for (int mf = 0; mf < 4; ++mf)
#pragma unroll
                for (int nf = 0; nf < 4; ++nf)
                    acc[mf][nf] = __builtin_amdgcn_mfma_f32_16x16x32_bf16(
                        af[mf], bf[nf], acc[mf][nf], 0, 0, 0);
        }
    }

    // epilogue: D row = (lane>>4)*4 + reg, col = lane&15
#pragma unroll
    for (int mf = 0; mf < 4; ++mf) {
#pragma unroll
        for (int r = 0; r < 4; ++r) {
            int m = m0 + wr * 64 + mf * 16 + lg * 4 + r;
            float bi = bias[m];
#pragma unroll
            for (int nf = 0; nf < 4; ++nf) {
                int n = n0 + wc * 64 + nf * 16 + lr;
                float v = acc[mf][nf][r] + bi;
                if (BF16OUT)
                    ((ushort*)Yg)[(size_t)b * M * N + (size_t)m * N + n] = f2bf(v);
                else
                    ((float*)Yg)[(size_t)b * M * N + (size_t)m * N + n] = v;
            }
        }
    }
}

// ---------------- fused dw5+gelu+dw3+gelu (LDS tiled, bf16 io) ----------------
__global__ __launch_bounds__(256) void k_dw_fused(
    const ushort* __restrict__ X, const float* __restrict__ W5,
    const float* __restrict__ B5, const float* __restrict__ W3,
    const float* __restrict__ B3, ushort* __restrict__ Y)
{
    const int b = blockIdx.z, ch = blockIdx.y;
    const int ty0 = (blockIdx.x >> 1) * 64, tx0 = (blockIdx.x & 1) * 64;
    __shared__ ushort in_s[70][72];
    __shared__ float  mid_s[66][68];
    const ushort* Xc = X + ((size_t)b * C6 + ch) * HW2;
    ushort* Yc = Y + ((size_t)b * C6 + ch) * HW2;
    const int tid = threadIdx.x;

    float w5[25], w3[9];
#pragma unroll
    for (int i = 0; i < 25; ++i) w5[i] = W5[ch * 25 + i];
#pragma unroll
    for (int i = 0; i < 9; ++i)  w3[i] = W3[ch * 9 + i];
    const float b5v = B5[ch], b3v = B3[ch];

    // load 70x70 input tile (halo 3), zero outside image / pad cols
    for (int e = tid; e < 70 * 72; e += 256) {
        int r = e / 72, c = e - r * 72;
        int gy = ty0 + r - 3, gx = tx0 + c - 3;
        ushort v = 0;
        if (c < 70 && (unsigned)gy < 128u && (unsigned)gx < 128u)
            v = Xc[gy * 128 + gx];
        in_s[r][c] = v;
    }
    __syncthreads();

    // stage 1: mid[66][66] (out-coord offset -1), 4-wide col groups
    for (int g = tid; g < 66 * 17; g += 256) {
        int r = g / 17, cg = g - r * 17;
        int c = cg * 4;
        float xin[5][8];
#pragma unroll
        for (int dr = 0; dr < 5; ++dr) {
            ushort4 lo = *(const ushort4*)&in_s[r + dr][c];
            ushort4 hi = *(const ushort4*)&in_s[r + dr][c + 4];
            xin[dr][0] = bf2f(lo.x); xin[dr][1] = bf2f(lo.y);
            xin[dr][2] = bf2f(lo.z); xin[dr][3] = bf2f(lo.w);
            xin[dr][4] = bf2f(hi.x); xin[dr][5] = bf2f(hi.y);
            xin[dr][6] = bf2f(hi.z); xin[dr][7] = bf2f(hi.w);
        }
        int gy = ty0 + r - 1;
        float o[4];
#pragma unroll
        for (int j = 0; j < 4; ++j) {
            float acc = b5v;
#pragma unroll
            for (int dr = 0; dr < 5; ++dr)
#pragma unroll
                for (int dc = 0; dc < 5; ++dc)
                    acc += xin[dr][j + dc] * w5[dr * 5 + dc];
            int gx = tx0 + c + j - 1;
            bool ok = ((unsigned)gy < 128u) && ((unsigned)gx < 128u);
            o[j] = ok ? gelu(acc) : 0.f;     // zero outside image (SAME pad for dw3)
        }
        *(float4*)&mid_s[r][c] = make_float4(o[0], o[1], o[2], o[3]);
    }
    __syncthreads();

    // stage 2: out 64x64, 4-wide col groups
    for (int g = tid; g < 64 * 16; g += 256) {
        int r = g >> 4, c = (g & 15) * 4;
        float mv[3][8];
#pragma unroll
        for (int dr = 0; dr < 3; ++dr) {
            float4 a = *(const float4*)&mid_s[r + dr][c];
            float4 bq = *(const float4*)&mid_s[r + dr][c + 4];
            mv[dr][0] = a.x; mv[dr][1] = a.y; mv[dr][2] = a.z; mv[dr][3] = a.w;
            mv[dr][4] = bq.x; mv[dr][5] = bq.y; mv[dr][6] = bq.z; mv[dr][7] = bq.w;
        }
        ushort4 ov;
        float oo[4];
#pragma unroll
        for (int j = 0; j < 4; ++j) {
            float acc = b3v;
#pragma unroll
            for (int dr = 0; dr < 3; ++dr)
#pragma unroll
                for (int dc = 0; dc < 3; ++dc)
                    acc += mv[dr][j + dc] * w3[dr * 3 + dc];
            oo[j] = gelu(acc);
        }
        ov.x = f2bf(oo[0]); ov.y = f2bf(oo[1]); ov.z = f2bf(oo[2]); ov.w = f2bf(oo[3]);
        *(ushort4*)&Yc[(ty0 + r) * 128 + tx0 + c] = ov;
    }
}

// ---------------- IDWT + global-mean partial sums ----------------
__global__ __launch_bounds__(256) void k_idwt(
    const float* __restrict__ S, const float* __restrict__ filt,
    float* __restrict__ Xw, float* __restrict__ sumbuf)
{
    const int b = blockIdx.z, c = blockIdx.y;
    const int tid = threadIdx.x;
    const int n = blockIdx.x * 256 + tid;
    const int h2 = n >> 7, w2 = n & 127;
    float f[16];
#pragma unroll
    for (int i = 0; i < 16; ++i) f[i] = filt[i];
    float sv[4];
#pragma unroll
    for (int k = 0; k < 4; ++k)
        sv[k] = S[((size_t)b * C4 + k * CDIM + c) * HW2 + n];
    float* xp = Xw + ((size_t)b * CDIM + c) * HW + (size_t)(2 * h2) * WDIM + 2 * w2;
    float local = 0.f;
#pragma unroll
    for (int p = 0; p < 2; ++p)
#pragma unroll
        for (int q = 0; q < 2; ++q) {
            float v = sv[0] * f[0*4 + p*2 + q] + sv[1] * f[1*4 + p*2 + q]
                    + sv[2] * f[2*4 + p*2 + q] + sv[3] * f[3*4 + p*2 + q];
            xp[p * WDIM + q] = v;
            local += v;
        }
    __shared__ float red[256];
    red[tid] = local;
    __syncthreads();
    for (int off = 128; off > 0; off >>= 1) {
        if (tid < off) red[tid] += red[tid + off];
        __syncthreads();
    }
    if (tid == 0) atomicAdd(&sumbuf[b * CDIM + c], red[0]);
}

// ---------------- SCA attention vector (tiny) ----------------
__global__ void k_att(const float* __restrict__ sumbuf, const float* __restrict__ Wsca,
                      const float* __restrict__ bsca, float* __restrict__ att)
{
    int t = threadIdx.x;
    int b = t >> 6, o = t & 63;
    float acc = bsca[o];
    const float s = 1.0f / (float)HW;
    for (int c = 0; c < 64; ++c)
        acc += Wsca[o * 64 + c] * (sumbuf[b * 64 + c] * s);
    att[t] = acc;
}

// ---------------- x*att -> pw3 -> y = x_in + x*beta ----------------
__global__ __launch_bounds__(256) void k_sca_pw3(
    const float* __restrict__ Xw, const float* __restrict__ Xin,
    const float* __restrict__ att, const float* __restrict__ W3,
    const float* __restrict__ b3, const float* __restrict__ beta,
    float* __restrict__ Yb)
{
    __shared__ __align__(16) float w3s[64 * 64];
    __shared__ float atts[64], b3s[64], bets[64];
    const int tid = threadIdx.x, b = blockIdx.z;
    for (int i = tid; i < 4096; i += 256) w3s[i] = W3[i];
    if (tid < 64) { atts[tid] = att[b * 64 + tid]; b3s[tid] = b3[tid]; bets[tid] = beta[tid]; }
    __syncthreads();
    const size_t n = (size_t)blockIdx.x * 256 + tid;
    const size_t base = (size_t)b * 64 * HW + n;
    float v[64];
#pragma unroll
    for (int c = 0; c < 64; ++c) v[c] = Xw[base + (size_t)c * HW] * atts[c];
    for (int o = 0; o < 64; ++o) {
        float acc = b3s[o];
        const float4* wr = (const float4*)&w3s[o * 64];
#pragma unroll
        for (int c4 = 0; c4 < 16; ++c4) {
            float4 wv = wr[c4]; int c = c4 * 4;
            acc += wv.x*v[c] + wv.y*v[c+1] + wv.z*v[c+2] + wv.w*v[c+3];
        }
        Yb[base + (size_t)o * HW] = Xin[base + (size_t)o * HW] + acc * bets[o];
    }
}

// ---------------- LN2 -> pw4 -> SimpleGate (h = a*g) ----------------
__global__ __launch_bounds__(256) void k_ln2_pw4(
    const float* __restrict__ Yb, const float* __restrict__ lw,
    const float* __restrict__ lb, const float* __restrict__ W4,
    const float* __restrict__ b4, float* __restrict__ Hb)
{
    __shared__ __align__(16) float w4s[128 * 64];
    __shared__ float b4s[128], lws[64], lbs[64];
    const int tid = threadIdx.x, b = blockIdx.z;
    for (int i = tid; i < 8192; i += 256) w4s[i] = W4[i];
    if (tid < 128) b4s[tid] = b4[tid];
    if (tid < 64) { lws[tid] = lw[tid]; lbs[tid] = lb[tid]; }
    __syncthreads();
    const size_t n = (size_t)blockIdx.x * 256 + tid;
    const size_t base = (size_t)b * 64 * HW + n;
    float t[64]; float sum = 0.f, sq = 0.f;
#pragma unroll
    for (int c = 0; c < 64; ++c) {
        float yv = Yb[base + (size_t)c * HW];
        t[c] = yv; sum += yv; sq += yv * yv;
    }
    float mu = sum * (1.0f / 64.0f);
    float var = sq * (1.0f / 64.0f) - mu * mu;
    float rs = rsqrtf(fmaxf(var, 0.f) + 1e-6f);
#pragma unroll
    for (int c = 0; c < 64; ++c) t[c] = (t[c] - mu) * rs * lws[c] + lbs[c];
    for (int j = 0; j < 64; ++j) {
        float aj = b4s[j], gj = b4s[j + 64];
        const float4* wa = (const float4*)&w4s[j * 64];
        const float4* wg = (const float4*)&w4s[(j + 64) * 64];
#pragma unroll
        for (int c4 = 0; c4 < 16; ++c4) {
            float4 va = wa[c4], vg = wg[c4]; int c = c4 * 4;
            aj += va.x*t[c] + va.y*t[c+1] + va.z*t[c+2] + va.w*t[c+3];
            gj += vg.x*t[c] + vg.y*t[c+1] + vg.z*t[c+2] + vg.w*t[c+3];
        }
        Hb[((size_t)b * 64 + j) * HW + n] = aj * gj;
    }
}

// ---------------- pw5 + final residual ----------------
__global__ __launch_bounds__(256) void k_pw5_out(
    const float* __restrict__ Yb, const float* __restrict__ Hb,
    const float* __restrict__ W5, const float* __restrict__ b5,
    const float* __restrict__ gamma, float* __restrict__ Out)
{
    __shared__ __align__(16) float w5s[64 * 64];
    __shared__ float b5s[64], gs[64];
    const int tid = threadIdx.x, b = blockIdx.z;
    for (int i = tid; i < 4096; i += 256) w5s[i] = W5[i];
    if (tid < 64) { b5s[tid] = b5[tid]; gs[tid] = gamma[tid]; }
    __syncthreads();
    const size_t n = (size_t)blockIdx.x * 256 + tid;
    const size_t base = (size_t)b * 64 * HW + n;
    float hv[64];
#pragma unroll
    for (int j = 0; j < 64; ++j) hv[j] = Hb[base + (size_t)j * HW];
    for (int o = 0; o < 64; ++o) {
        float acc = b5s[o];
        const float4* wr = (const float4*)&w5s[o * 64];
#pragma unroll
        for (int j4 = 0; j4 < 16; ++j4) {
            float4 wv = wr[j4]; int j = j4 * 4;
            acc += wv.x*hv[j] + wv.y*hv[j+1] + wv.z*hv[j+2] + wv.w*hv[j+3];
        }
        Out[base + (size_t)o * HW] = Yb[base + (size_t)o * HW] + acc * gs[o];
    }
}

extern "C" void kernel_launch(void* const* d_in, const int* in_sizes, int n_in,
                              void* d_out, int out_size, void* d_ws, size_t ws_size,
                              hipStream_t stream) {
    const float* x_in  = (const float*)d_in[0];
    const float* filt  = (const float*)d_in[1];
    const float* ln1_w = (const float*)d_in[2];
    const float* ln1_b = (const float*)d_in[3];
    const float* w1    = (const float*)d_in[4];
    const float* b1    = (const float*)d_in[5];
    const float* dw5   = (const float*)d_in[6];
    const float* bdw5  = (const float*)d_in[7];
    const float* dw3   = (const float*)d_in[8];
    const float* bdw3  = (const float*)d_in[9];
    const float* w2    = (const float*)d_in[10];
    const float* b2    = (const float*)d_in[11];
    const float* w_sca = (const float*)d_in[12];
    const float* b_sca = (const float*)d_in[13];
    const float* w3    = (const float*)d_in[14];
    const float* b3    = (const float*)d_in[15];
    const float* beta  = (const float*)d_in[16];
    const float* ln2_w = (const float*)d_in[17];
    const float* ln2_b = (const float*)d_in[18];
    const float* w4    = (const float*)d_in[19];
    const float* b4    = (const float*)d_in[20];
    const float* w5    = (const float*)d_in[21];
    const float* b5    = (const float*)d_in[22];
    const float* gamma = (const float*)d_in[23];
    float* out = (float*)d_out;

    // per-batch region = 16 MiB (holds any of: S bf16 8.4MB, p1/d3 bf16 12.6MB,
    // p2 f32 16.8MB, xw/y/h f32 16.8MB)
    const size_t PB = (size_t)CDIM * HW * 4;   // 16,777,216 B
    int bc = 8;
    while (bc > 1 && 3 * PB * (size_t)bc + 512 * 1024 > ws_size) bc >>= 1;
    const int nchunk = BDIM / bc;

    char* base = (char*)d_ws;
    char* R1 = base;
    char* R2 = base + PB * bc;
    char* R3 = base + 2 * PB * bc;
    ushort* w1b  = (ushort*)(base + 3 * PB * bc);
    ushort* w2b  = w1b + C6 * C4;
    float*  stats = (float*)(w2b + C6 * C4);
    float*  attv  = stats + (size_t)bc * 64;

    // weight conversion (every call; ws is re-poisoned)
    k_cvt_bf16<<<(C6 * C4 + 255) / 256, 256, 0, stream>>>(w1, w1b, C6 * C4);
    k_cvt_bf16<<<(C6 * C4 + 255) / 256, 256, 0, stream>>>(w2, w2b, C6 * C4);

    // packed views (lifetimes verified):
    ushort* S   = (ushort*)R1;  // ln_dwt -> pw1
    ushort* p1  = (ushort*)R2;  // pw1 -> dw
    ushort* d3  = (ushort*)R1;  // dw -> pw2      (S dead)
    float*  p2  = (float*)R2;   // pw2 -> idwt    (p1 dead)
    float*  xw  = (float*)R3;   // idwt -> sca
    float*  yb  = (float*)R1;   // sca -> pw5     (d3 dead)
    float*  hb  = (float*)R2;   // ln2 -> pw5     (p2 dead)

    for (int ck = 0; ck < nchunk; ++ck) {
        const float* xin_c = x_in + (size_t)ck * bc * CDIM * HW;
        float* out_c = out + (size_t)ck * bc * CDIM * HW;

        hipMemsetAsync(stats, 0, (size_t)bc * 64 * sizeof(float), stream);

        k_ln_dwt<<<dim3(128, 1, bc), 256, 0, stream>>>(xin_c, filt, ln1_w, ln1_b, S);
        k_pw_mfma<true ><<<dim3(128, 3, bc), 256, 0, stream>>>(w1b, b1, S,  (void*)p1, C6, C4, HW2);
        k_dw_fused<<<dim3(4, C6, bc), 256, 0, stream>>>(p1, dw5, bdw5, dw3, bdw3, d3);
        k_pw_mfma<false><<<dim3(128, 2, bc), 256, 0, stream>>>(w2b, b2, d3, (void*)p2, C4, C6, HW2);
        k_idwt<<<dim3(64, CDIM, bc), 256, 0, stream>>>(p2, filt, xw, stats);
        k_att<<<1, bc * 64, 0, stream>>>(stats, w_sca, b_sca, attv);
        k_sca_pw3<<<dim3(256, 1, bc), 256, 0, stream>>>(xw, xin_c, attv, w3, b3, beta, yb);
        k_ln2_pw4<<<dim3(256, 1, bc), 256, 0, stream>>>(yb, ln2_w, ln2_b, w4, b4, hb);
        k_pw5_out<<<dim3(256, 1, bc), 256, 0, stream>>>(yb, hb, w5, b5, gamma, out_c);
    }
}